// Round 11
// baseline (719.255 us; speedup 1.0000x reference)
//
#include <hip/hip_runtime.h>
#include <hip/hip_bf16.h>

#define OUT_DIM 4096
#define IN_DIM  4096
#define RANK    64
#define M_DIM   16384   // B*S = 4*4096

typedef short  s16x8 __attribute__((ext_vector_type(8)));
typedef __bf16 b16x8 __attribute__((ext_vector_type(8)));
typedef float  f32x4 __attribute__((ext_vector_type(4)));

// ---- MFMA wrapper: tolerate either builtin signature (short8 or bf16x8) ----
template <typename T>
__device__ static inline auto mfma_sel(T a, T b, f32x4 c, int)
    -> decltype(__builtin_amdgcn_mfma_f32_16x16x32_bf16(a, b, c, 0, 0, 0)) {
  return __builtin_amdgcn_mfma_f32_16x16x32_bf16(a, b, c, 0, 0, 0);
}
template <typename T>
__device__ static inline f32x4 mfma_sel(T a, T b, f32x4 c, long) {
  return __builtin_amdgcn_mfma_f32_16x16x32_bf16(
      __builtin_bit_cast(b16x8, a), __builtin_bit_cast(b16x8, b), c, 0, 0, 0);
}
__device__ static inline f32x4 mfma_bf16(s16x8 a, s16x8 b, f32x4 c) {
  return mfma_sel(a, b, c, 0);
}

// ---- fp32 -> bf16 bits, round-to-nearest-even ----
__device__ static inline unsigned short f2bf(float f) {
  unsigned int u = __float_as_uint(f);
  u += 0x7fffu + ((u >> 16) & 1u);
  return (unsigned short)(u >> 16);
}

// ---- async global->LDS, 16B per lane ----
__device__ static inline void gload16(const unsigned short* g, unsigned short* l) {
  __builtin_amdgcn_global_load_lds(
      (const __attribute__((address_space(1))) void*)g,
      (__attribute__((address_space(3))) void*)l, 16, 0, 0);
}

// ============ kernel 1: RV2 = diag(S_tail) * (R @ Vh_tail)  (64 x IN) ========
__global__ void rv2_kernel(const float* __restrict__ Rm, const float* __restrict__ Vh_tail,
                           const float* __restrict__ S_tail, float* __restrict__ RV2) {
  const int i  = blockIdx.x * 256 + threadIdx.x;  // 0..IN_DIM-1
  const int r0 = blockIdx.y * 8;
  float acc[8] = {};
  for (int q = 0; q < RANK; ++q) {
    float v = Vh_tail[(size_t)q * IN_DIM + i];
#pragma unroll
    for (int rr = 0; rr < 8; ++rr)
      acc[rr] = fmaf(Rm[(r0 + rr) * RANK + q], v, acc[rr]);   // uniform -> s_load
  }
#pragma unroll
  for (int rr = 0; rr < 8; ++rr)
    RV2[(size_t)(r0 + rr) * IN_DIM + i] = acc[rr] * S_tail[r0 + rr];
}

// ============ kernel 2: FUSED  cvt (x->bf16)  +  W_tilde build ==============
#define CVT_BLOCKS 2048
#define WT_O 16
#define WT_BLOCKS ((IN_DIM / 256) * (OUT_DIM / WT_O))   // 4096
__global__ void prep_fused_kernel(const float* __restrict__ x, unsigned short* __restrict__ xb,
                                  const float* __restrict__ W,      const float* __restrict__ U_top,
                                  const float* __restrict__ S_top,  const float* __restrict__ alpha,
                                  const float* __restrict__ beta,   const float* __restrict__ U_tail,
                                  const float* __restrict__ Vh_top, const float* __restrict__ RV2,
                                  unsigned short* __restrict__ Wb) {
  const int tid = threadIdx.x;
  if (blockIdx.x < CVT_BLOCKS) {
    // ---- cvt half ----
    const long long n8 = (long long)M_DIM * IN_DIM / 8;
    long long idx = (long long)blockIdx.x * 256 + tid;
    const long long stride = (long long)CVT_BLOCKS * 256;
    for (; idx < n8; idx += stride) {
      const f32x4* p = (const f32x4*)(x + idx * 8);
      f32x4 v0 = p[0], v1 = p[1];
      s16x8 o;
      o[0] = (short)f2bf(v0[0]); o[1] = (short)f2bf(v0[1]);
      o[2] = (short)f2bf(v0[2]); o[3] = (short)f2bf(v0[3]);
      o[4] = (short)f2bf(v1[0]); o[5] = (short)f2bf(v1[1]);
      o[6] = (short)f2bf(v1[2]); o[7] = (short)f2bf(v1[3]);
      *(s16x8*)(xb + idx * 8) = o;
    }
  } else {
    // ---- wtilde half ----
    const int rem = blockIdx.x - CVT_BLOCKS;
    const int i   = (rem & 15) * 256 + tid;      // 0..IN_DIM-1
    const int o0  = (rem >> 4) * WT_O;           // 0..OUT_DIM-16
    float acc[WT_O];
#pragma unroll
    for (int o = 0; o < WT_O; ++o) acc[o] = W[(size_t)(o0 + o) * IN_DIM + i];
#pragma unroll 4
    for (int r = 0; r < RANK; ++r) {
      float sig = fmaxf(fmaf(S_top[r], alpha[r], beta[r]), 0.f);   // uniform
      float vt  = Vh_top[(size_t)r * IN_DIM + i] * sig;
      float rv  = RV2[(size_t)r * IN_DIM + i];
#pragma unroll
      for (int o = 0; o < WT_O; ++o) {
        acc[o] = fmaf(U_top[(o0 + o) * RANK + r],  vt, acc[o]);    // uniform -> s_load
        acc[o] = fmaf(U_tail[(o0 + o) * RANK + r], rv, acc[o]);
      }
    }
#pragma unroll
    for (int o = 0; o < WT_O; ++o)
      Wb[(size_t)(o0 + o) * IN_DIM + i] = f2bf(acc[o]);
  }
}

// ============ kernel 3: 256x256 8-phase GEMM, early-issue staging ===========
// R3-proven skeleton (reads, barriers, publication points identical).
// ONLY change: staging issue order + wait counts.
//   q0: B0,B1,B2,B3(t+1)   q1: A0,A2,A1,A3(t+1)   q2,q3: no issues
// Ledger (steady state, queue oldest->newest):
//   entry: {A1,A3(t)} (2) -> q0 +4B -> 6 -> q1 +4A -> 10
//   q1-end vmcnt(8): completes A1,A3(t) (issued 6 phases ago - free wait);
//                    publishes rows for phases 2,3 at the closing barrier.
//   q3-end vmcnt(2): completes B*,A0,A2(t+1) (issued 2-3 phases ago,
//                    ~500-700cy cover vs R3's ~200cy); leaves {A1,A3(t+1)}.
#define BM 256
#define BN 256
#define BK 64
#define NT (IN_DIM / BK)   // 64

__global__ __launch_bounds__(512, 2) void gemm_kernel(
    const unsigned short* __restrict__ A,   // xb [M][K] bf16 bits
    const unsigned short* __restrict__ Bw,  // Wb [N][K] bf16 bits
    const float* __restrict__ bias,
    float* __restrict__ C) {
  __shared__ unsigned short lds[2][2][BM * BK];   // 128 KiB

  const int tid = threadIdx.x;
  const int l   = tid & 63;
  const int wid = tid >> 6;
  const int wr  = wid >> 2;                 // 0..1  (M split)
  const int wc  = wid & 3;                  // 0..3  (N split)

  // XCD swizzle: 1024 blocks, 8 XCDs, nwg%8==0 -> simple bijection.
  const int bid = blockIdx.x;
  const int swz = (bid & 7) * 128 + (bid >> 3);
  const int nt_ = swz >> 6;                 // 0..15
  const int mt_ = swz & 63;                 // 0..63
  const long long tileM = (long long)mt_ * BM;
  const long long tileN = (long long)nt_ * BN;

  // ---- staging geometry (linear LDS dest, inverse-swizzled global src) ----
  const int rbase = tid >> 3;
  const int c8    = (((tid & 7) ^ (rbase & 7)) << 3);
  const unsigned short* gA = A  + (tileM + rbase) * (long long)IN_DIM + c8;
  const unsigned short* gB = Bw + (tileN + rbase) * (long long)IN_DIM + c8;

  // ---- ds_read geometry ----
  const int kgrp = l >> 4;                  // 0..3
  const int x7   = l & 7;
  const int sc0  = (((0 * 4 + kgrp) ^ x7) << 3);
  const int sc1  = (((1 * 4 + kgrp) ^ x7) << 3);
  const int rba  = (wr * 128 + (l & 15)) * BK;
  const int rbb  = (wc * 64  + (l & 15)) * BK;

  f32x4 acc[8][4] = {};

  // ---- prologue: stage tile 0 fully, drain, barrier ----
  {
    unsigned short* la = &lds[0][0][tid * 8];
    unsigned short* lb = &lds[0][1][tid * 8];
#pragma unroll
    for (int j = 0; j < 4; ++j) {
      gload16(gB + (long long)j * 64 * IN_DIM, lb + j * 4096);
      gload16(gA + (long long)j * 64 * IN_DIM, la + j * 4096);
    }
    asm volatile("s_waitcnt vmcnt(0)" ::: "memory");
    asm volatile("s_barrier" ::: "memory");
  }

  int buf = 0;
  for (int t = 0; t < NT; ++t) {
    const long long ktn = (long long)(t + 1) * BK;
    const bool more = (t + 1 < NT);
    const unsigned short* lA = lds[buf][0];
    const unsigned short* lB = lds[buf][1];
    unsigned short* la1 = &lds[buf ^ 1][0][tid * 8];
    unsigned short* lb1 = &lds[buf ^ 1][1][tid * 8];

    s16x8 bfr[4][2];
#pragma unroll
    for (int q = 0; q < 4; ++q) {
      // --- ds reads for this phase (placement identical to R3) ---
      if (q == 0) {
#pragma unroll
        for (int n = 0; n < 4; ++n) {
          bfr[n][0] = *(const s16x8*)&lB[rbb + n * 16 * BK + sc0];
          bfr[n][1] = *(const s16x8*)&lB[rbb + n * 16 * BK + sc1];
        }
      }
      s16x8 afr[2][2];
#pragma unroll
      for (int m2 = 0; m2 < 2; ++m2) {
        afr[m2][0] = *(const s16x8*)&lA[rba + (q * 32 + m2 * 16) * BK + sc0];
        afr[m2][1] = *(const s16x8*)&lA[rba + (q * 32 + m2 * 16) * BK + sc1];
      }

      // --- early-issue staging: all B at q0, all A at q1 ---
      if (more) {
        if (q == 0) {
          gload16(gB + ktn, lb1);
          gload16(gB + ktn + 1LL * 64 * IN_DIM, lb1 + 4096);
          gload16(gB + ktn + 2LL * 64 * IN_DIM, lb1 + 2 * 4096);
          gload16(gB + ktn + 3LL * 64 * IN_DIM, lb1 + 3 * 4096);
        } else if (q == 1) {
          gload16(gA + ktn, la1);                                 // A0
          gload16(gA + ktn + 2LL * 64 * IN_DIM, la1 + 2 * 4096);  // A2
          gload16(gA + ktn + 1LL * 64 * IN_DIM, la1 + 1 * 4096);  // A1
          gload16(gA + ktn + 3LL * 64 * IN_DIM, la1 + 3 * 4096);  // A3
        }
      }

      asm volatile("s_barrier" ::: "memory");

      __builtin_amdgcn_s_setprio(1);
#pragma unroll
      for (int m2 = 0; m2 < 2; ++m2)
#pragma unroll
        for (int n = 0; n < 4; ++n)
#pragma unroll
          for (int kk = 0; kk < 2; ++kk)
            acc[q * 2 + m2][n] = mfma_bf16(afr[m2][kk], bfr[n][kk], acc[q * 2 + m2][n]);
      __builtin_amdgcn_s_setprio(0);

      // --- counted waits (never 0 in steady state) ---
      if (q == 1) {
        if (more) asm volatile("s_waitcnt vmcnt(8)" ::: "memory");
        else      asm volatile("s_waitcnt vmcnt(0)" ::: "memory");
      }
      if (q == 3 && more) {
        asm volatile("s_waitcnt vmcnt(2)" ::: "memory");
      }
      asm volatile("s_barrier" ::: "memory");
    }
    buf ^= 1;
  }

  // ---- epilogue: D row = m*16 + (l>>4)*4 + r ; col = n*16 + (l&15) ----
  float bv[4];
#pragma unroll
  for (int n = 0; n < 4; ++n) bv[n] = bias[tileN + wc * 64 + n * 16 + (l & 15)];
#pragma unroll
  for (int m = 0; m < 8; ++m) {
    const long long rbase_c = tileM + wr * 128 + m * 16 + (l >> 4) * 4;
#pragma unroll
    for (int r = 0; r < 4; ++r) {
      float* crow = C + (size_t)(rbase_c + r) * OUT_DIM + tileN + wc * 64 + (l & 15);
#pragma unroll
      for (int n = 0; n < 4; ++n) crow[n * 16] = acc[m][n][r] + bv[n];
    }
  }
}

extern "C" void kernel_launch(void* const* d_in, const int* in_sizes, int n_in,
                              void* d_out, int out_size, void* d_ws, size_t ws_size,
                              hipStream_t stream) {
  const float* x       = (const float*)d_in[0];
  const float* W       = (const float*)d_in[1];
  const float* bias    = (const float*)d_in[2];
  const float* U_top   = (const float*)d_in[3];
  const float* S_top   = (const float*)d_in[4];
  const float* Vh_top  = (const float*)d_in[5];
  const float* U_tail  = (const float*)d_in[6];
  const float* S_tail  = (const float*)d_in[7];
  const float* Vh_tail = (const float*)d_in[8];
  const float* alpha   = (const float*)d_in[9];
  const float* beta    = (const float*)d_in[10];
  const float* Rm      = (const float*)d_in[11];

  char* ws = (char*)d_ws;
  unsigned short* xb  = (unsigned short*)ws;                                  // 128 MB
  unsigned short* Wb  = (unsigned short*)(ws + (size_t)134217728);            // 32 MB
  float*          RV2 = (float*)(ws + (size_t)134217728 + 33554432);          // 1 MB

  rv2_kernel<<<dim3(IN_DIM / 256, RANK / 8), 256, 0, stream>>>(Rm, Vh_tail, S_tail, RV2);
  prep_fused_kernel<<<CVT_BLOCKS + WT_BLOCKS, 256, 0, stream>>>(
      x, xb, W, U_top, S_top, alpha, beta, U_tail, Vh_top, RV2, Wb);
  gemm_kernel<<<(M_DIM / BM) * (OUT_DIM / BN), 512, 0, stream>>>(xb, Wb, bias,
                                                                 (float*)d_out);
}

// Round 12
// 697.549 us; speedup vs baseline: 1.0311x; 1.0311x over previous
//
#include <hip/hip_runtime.h>
#include <hip/hip_bf16.h>

#define OUT_DIM 4096
#define IN_DIM  4096
#define RANK    64
#define M_DIM   16384   // B*S = 4*4096

typedef short  s16x8 __attribute__((ext_vector_type(8)));
typedef __bf16 b16x8 __attribute__((ext_vector_type(8)));
typedef float  f32x4 __attribute__((ext_vector_type(4)));

// ---- MFMA wrapper: tolerate either builtin signature (short8 or bf16x8) ----
template <typename T>
__device__ static inline auto mfma_sel(T a, T b, f32x4 c, int)
    -> decltype(__builtin_amdgcn_mfma_f32_16x16x32_bf16(a, b, c, 0, 0, 0)) {
  return __builtin_amdgcn_mfma_f32_16x16x32_bf16(a, b, c, 0, 0, 0);
}
template <typename T>
__device__ static inline f32x4 mfma_sel(T a, T b, f32x4 c, long) {
  return __builtin_amdgcn_mfma_f32_16x16x32_bf16(
      __builtin_bit_cast(b16x8, a), __builtin_bit_cast(b16x8, b), c, 0, 0, 0);
}
__device__ static inline f32x4 mfma_bf16(s16x8 a, s16x8 b, f32x4 c) {
  return mfma_sel(a, b, c, 0);
}

// ---- fp32 -> bf16 bits, round-to-nearest-even ----
__device__ static inline unsigned short f2bf(float f) {
  unsigned int u = __float_as_uint(f);
  u += 0x7fffu + ((u >> 16) & 1u);
  return (unsigned short)(u >> 16);
}

// ---- async global->LDS, 16B per lane ----
__device__ static inline void gload16(const unsigned short* g, unsigned short* l) {
  __builtin_amdgcn_global_load_lds(
      (const __attribute__((address_space(1))) void*)g,
      (__attribute__((address_space(3))) void*)l, 16, 0, 0);
}

// ============ kernel 1: RV2 = diag(S_tail) * (R @ Vh_tail)  (64 x IN) ========
__global__ void rv2_kernel(const float* __restrict__ Rm, const float* __restrict__ Vh_tail,
                           const float* __restrict__ S_tail, float* __restrict__ RV2) {
  const int i  = blockIdx.x * 256 + threadIdx.x;  // 0..IN_DIM-1
  const int r0 = blockIdx.y * 8;
  float acc[8] = {};
  for (int q = 0; q < RANK; ++q) {
    float v = Vh_tail[(size_t)q * IN_DIM + i];
#pragma unroll
    for (int rr = 0; rr < 8; ++rr)
      acc[rr] = fmaf(Rm[(r0 + rr) * RANK + q], v, acc[rr]);   // uniform -> s_load
  }
#pragma unroll
  for (int rr = 0; rr < 8; ++rr)
    RV2[(size_t)(r0 + rr) * IN_DIM + i] = acc[rr] * S_tail[r0 + rr];
}

// ============ kernel 2: FUSED  cvt (x->bf16)  +  W_tilde build ==============
#define CVT_BLOCKS 2048
#define WT_O 16
#define WT_BLOCKS ((IN_DIM / 256) * (OUT_DIM / WT_O))   // 4096
__global__ void prep_fused_kernel(const float* __restrict__ x, unsigned short* __restrict__ xb,
                                  const float* __restrict__ W,      const float* __restrict__ U_top,
                                  const float* __restrict__ S_top,  const float* __restrict__ alpha,
                                  const float* __restrict__ beta,   const float* __restrict__ U_tail,
                                  const float* __restrict__ Vh_top, const float* __restrict__ RV2,
                                  unsigned short* __restrict__ Wb) {
  const int tid = threadIdx.x;
  if (blockIdx.x < CVT_BLOCKS) {
    // ---- cvt half ----
    const long long n8 = (long long)M_DIM * IN_DIM / 8;
    long long idx = (long long)blockIdx.x * 256 + tid;
    const long long stride = (long long)CVT_BLOCKS * 256;
    for (; idx < n8; idx += stride) {
      const f32x4* p = (const f32x4*)(x + idx * 8);
      f32x4 v0 = p[0], v1 = p[1];
      s16x8 o;
      o[0] = (short)f2bf(v0[0]); o[1] = (short)f2bf(v0[1]);
      o[2] = (short)f2bf(v0[2]); o[3] = (short)f2bf(v0[3]);
      o[4] = (short)f2bf(v1[0]); o[5] = (short)f2bf(v1[1]);
      o[6] = (short)f2bf(v1[2]); o[7] = (short)f2bf(v1[3]);
      *(s16x8*)(xb + idx * 8) = o;
    }
  } else {
    // ---- wtilde half ----
    const int rem = blockIdx.x - CVT_BLOCKS;
    const int i   = (rem & 15) * 256 + tid;      // 0..IN_DIM-1
    const int o0  = (rem >> 4) * WT_O;           // 0..OUT_DIM-16
    float acc[WT_O];
#pragma unroll
    for (int o = 0; o < WT_O; ++o) acc[o] = W[(size_t)(o0 + o) * IN_DIM + i];
#pragma unroll 4
    for (int r = 0; r < RANK; ++r) {
      float sig = fmaxf(fmaf(S_top[r], alpha[r], beta[r]), 0.f);   // uniform
      float vt  = Vh_top[(size_t)r * IN_DIM + i] * sig;
      float rv  = RV2[(size_t)r * IN_DIM + i];
#pragma unroll
      for (int o = 0; o < WT_O; ++o) {
        acc[o] = fmaf(U_top[(o0 + o) * RANK + r],  vt, acc[o]);    // uniform -> s_load
        acc[o] = fmaf(U_tail[(o0 + o) * RANK + r], rv, acc[o]);
      }
    }
#pragma unroll
    for (int o = 0; o < WT_O; ++o)
      Wb[(size_t)(o0 + o) * IN_DIM + i] = f2bf(acc[o]);
  }
}

// ============ kernel 3: 256x256 8-phase GEMM ================================
// R3/R10-proven skeleton (reads, staging order q0:B01 q1:B23 q2:A02 q3:A13,
// waits vmcnt(4)@q1 / vmcnt(2)@q3). Changes this round:
//  (a) builtin s_barrier + naked s_waitcnt (no "memory" clobber) -> scheduler
//      freedom across phase boundaries (m201 style);
//      sched_barrier(0) at the 3 publication fences blocks illegal ds_read
//      hoists (all other hoists blocked by may-alias gload_lds writes).
//  (b) XCD remap 4(M-groups of 16 tiles) x 2(N-groups of 8 panels), m-fastest:
//      per-XCD set = 32MB A + 16MB B; B panel (2MB) L2-resident per sweep.
#define BM 256
#define BN 256
#define BK 64
#define NT (IN_DIM / BK)   // 64

__global__ __launch_bounds__(512, 2) void gemm_kernel(
    const unsigned short* __restrict__ A,   // xb [M][K] bf16 bits
    const unsigned short* __restrict__ Bw,  // Wb [N][K] bf16 bits
    const float* __restrict__ bias,
    float* __restrict__ C) {
  __shared__ unsigned short lds[2][2][BM * BK];   // 128 KiB

  const int tid = threadIdx.x;
  const int l   = tid & 63;
  const int wid = tid >> 6;
  const int wr  = wid >> 2;                 // 0..1  (M split)
  const int wc  = wid & 3;                  // 0..3  (N split)

  // ---- XCD remap: xcd = bid&7 -> (mg, ng) = (xcd>>1, xcd&1); j = bid>>3 ----
  // mt = mg*16 + (j&15)  [m fastest -> B panel reuse in L2]
  // nt = ng*8  + (j>>4)
  const int bid = blockIdx.x;
  const int xcd = bid & 7;
  const int j   = bid >> 3;                 // 0..127
  const int mt_ = (xcd >> 1) * 16 + (j & 15);
  const int nt_ = (xcd & 1) * 8 + (j >> 4);
  const long long tileM = (long long)mt_ * BM;
  const long long tileN = (long long)nt_ * BN;

  // ---- staging geometry (linear LDS dest, inverse-swizzled global src) ----
  const int rbase = tid >> 3;
  const int c8    = (((tid & 7) ^ (rbase & 7)) << 3);
  const unsigned short* gA = A  + (tileM + rbase) * (long long)IN_DIM + c8;
  const unsigned short* gB = Bw + (tileN + rbase) * (long long)IN_DIM + c8;

  // ---- ds_read geometry ----
  const int kgrp = l >> 4;                  // 0..3
  const int x7   = l & 7;
  const int sc0  = (((0 * 4 + kgrp) ^ x7) << 3);
  const int sc1  = (((1 * 4 + kgrp) ^ x7) << 3);
  const int rba  = (wr * 128 + (l & 15)) * BK;
  const int rbb  = (wc * 64  + (l & 15)) * BK;

  f32x4 acc[8][4] = {};

  // ---- prologue: stage tile 0 fully, drain, barrier ----
  {
    unsigned short* la = &lds[0][0][tid * 8];
    unsigned short* lb = &lds[0][1][tid * 8];
#pragma unroll
    for (int jj = 0; jj < 4; ++jj) {
      gload16(gB + (long long)jj * 64 * IN_DIM, lb + jj * 4096);
      gload16(gA + (long long)jj * 64 * IN_DIM, la + jj * 4096);
    }
    asm volatile("s_waitcnt vmcnt(0)");
    __builtin_amdgcn_s_barrier();
    __builtin_amdgcn_sched_barrier(0);      // publication fence: tile 0
  }

  int buf = 0;
  for (int t = 0; t < NT; ++t) {
    const long long ktn = (long long)(t + 1) * BK;
    const bool more = (t + 1 < NT);
    const unsigned short* lA = lds[buf][0];
    const unsigned short* lB = lds[buf][1];
    unsigned short* la1 = &lds[buf ^ 1][0][tid * 8];
    unsigned short* lb1 = &lds[buf ^ 1][1][tid * 8];

    s16x8 bfr[4][2];
#pragma unroll
    for (int q = 0; q < 4; ++q) {
      // --- ds reads for this phase (placement identical to R3) ---
      if (q == 0) {
#pragma unroll
        for (int n = 0; n < 4; ++n) {
          bfr[n][0] = *(const s16x8*)&lB[rbb + n * 16 * BK + sc0];
          bfr[n][1] = *(const s16x8*)&lB[rbb + n * 16 * BK + sc1];
        }
      }
      s16x8 afr[2][2];
#pragma unroll
      for (int m2 = 0; m2 < 2; ++m2) {
        afr[m2][0] = *(const s16x8*)&lA[rba + (q * 32 + m2 * 16) * BK + sc0];
        afr[m2][1] = *(const s16x8*)&lA[rba + (q * 32 + m2 * 16) * BK + sc1];
      }

      // --- stage item q of tile t+1 into buf^1 (R3 order) ---
      if (more) {
        if (q == 0) {
          gload16(gB + ktn, lb1);
          gload16(gB + ktn + 1LL * 64 * IN_DIM, lb1 + 4096);
        } else if (q == 1) {
          gload16(gB + ktn + 2LL * 64 * IN_DIM, lb1 + 2 * 4096);
          gload16(gB + ktn + 3LL * 64 * IN_DIM, lb1 + 3 * 4096);
        } else if (q == 2) {
          gload16(gA + ktn, la1);
          gload16(gA + ktn + 2LL * 64 * IN_DIM, la1 + 2 * 4096);
        } else {
          gload16(gA + ktn + 1LL * 64 * IN_DIM, la1 + 1 * 4096);
          gload16(gA + ktn + 3LL * 64 * IN_DIM, la1 + 3 * 4096);
        }
      }

      __builtin_amdgcn_s_barrier();

      __builtin_amdgcn_s_setprio(1);
#pragma unroll
      for (int m2 = 0; m2 < 2; ++m2)
#pragma unroll
        for (int n = 0; n < 4; ++n)
#pragma unroll
          for (int kk = 0; kk < 2; ++kk)
            acc[q * 2 + m2][n] = mfma_bf16(afr[m2][kk], bfr[n][kk], acc[q * 2 + m2][n]);
      __builtin_amdgcn_s_setprio(0);

      // --- counted waits (never 0 in steady state) ---
      if (q == 1) {
        if (more) asm volatile("s_waitcnt vmcnt(4)");
        else      asm volatile("s_waitcnt vmcnt(0)");
      }
      if (q == 3 && more) {
        asm volatile("s_waitcnt vmcnt(2)");
      }
      __builtin_amdgcn_s_barrier();
      if (q == 1 || q == 3) {
        __builtin_amdgcn_sched_barrier(0);  // publication fences: A1,A3(t) / tile t+1
      }
    }
    buf ^= 1;
  }

  // ---- epilogue: D row = m*16 + (l>>4)*4 + r ; col = n*16 + (l&15) ----
  float bv[4];
#pragma unroll
  for (int n = 0; n < 4; ++n) bv[n] = bias[tileN + wc * 64 + n * 16 + (l & 15)];
#pragma unroll
  for (int m = 0; m < 8; ++m) {
    const long long rbase_c = tileM + wr * 128 + m * 16 + (l >> 4) * 4;
#pragma unroll
    for (int r = 0; r < 4; ++r) {
      float* crow = C + (size_t)(rbase_c + r) * OUT_DIM + tileN + wc * 64 + (l & 15);
#pragma unroll
      for (int n = 0; n < 4; ++n) crow[n * 16] = acc[m][n][r] + bv[n];
    }
  }
}

extern "C" void kernel_launch(void* const* d_in, const int* in_sizes, int n_in,
                              void* d_out, int out_size, void* d_ws, size_t ws_size,
                              hipStream_t stream) {
  const float* x       = (const float*)d_in[0];
  const float* W       = (const float*)d_in[1];
  const float* bias    = (const float*)d_in[2];
  const float* U_top   = (const float*)d_in[3];
  const float* S_top   = (const float*)d_in[4];
  const float* Vh_top  = (const float*)d_in[5];
  const float* U_tail  = (const float*)d_in[6];
  const float* S_tail  = (const float*)d_in[7];
  const float* Vh_tail = (const float*)d_in[8];
  const float* alpha   = (const float*)d_in[9];
  const float* beta    = (const float*)d_in[10];
  const float* Rm      = (const float*)d_in[11];

  char* ws = (char*)d_ws;
  unsigned short* xb  = (unsigned short*)ws;                                  // 128 MB
  unsigned short* Wb  = (unsigned short*)(ws + (size_t)134217728);            // 32 MB
  float*          RV2 = (float*)(ws + (size_t)134217728 + 33554432);          // 1 MB

  rv2_kernel<<<dim3(IN_DIM / 256, RANK / 8), 256, 0, stream>>>(Rm, Vh_tail, S_tail, RV2);
  prep_fused_kernel<<<CVT_BLOCKS + WT_BLOCKS, 256, 0, stream>>>(
      x, xb, W, U_top, S_top, alpha, beta, U_tail, Vh_top, RV2, Wb);
  gemm_kernel<<<(M_DIM / BM) * (OUT_DIM / BN), 512, 0, stream>>>(xb, Wb, bias,
                                                                 (float*)d_out);
}

// Round 13
// 632.633 us; speedup vs baseline: 1.1369x; 1.1026x over previous
//
#include <hip/hip_runtime.h>
#include <hip/hip_bf16.h>

#define OUT_DIM 4096
#define IN_DIM  4096
#define RANK    64
#define M_DIM   16384   // B*S = 4*4096

typedef short  s16x8 __attribute__((ext_vector_type(8)));
typedef __bf16 b16x8 __attribute__((ext_vector_type(8)));
typedef float  f32x4 __attribute__((ext_vector_type(4)));
typedef unsigned short u16x4 __attribute__((ext_vector_type(4)));

// ---- MFMA wrapper: tolerate either builtin signature (short8 or bf16x8) ----
template <typename T>
__device__ static inline auto mfma_sel(T a, T b, f32x4 c, int)
    -> decltype(__builtin_amdgcn_mfma_f32_16x16x32_bf16(a, b, c, 0, 0, 0)) {
  return __builtin_amdgcn_mfma_f32_16x16x32_bf16(a, b, c, 0, 0, 0);
}
template <typename T>
__device__ static inline f32x4 mfma_sel(T a, T b, f32x4 c, long) {
  return __builtin_amdgcn_mfma_f32_16x16x32_bf16(
      __builtin_bit_cast(b16x8, a), __builtin_bit_cast(b16x8, b), c, 0, 0, 0);
}
__device__ static inline f32x4 mfma_bf16(s16x8 a, s16x8 b, f32x4 c) {
  return mfma_sel(a, b, c, 0);
}

// ---- fp32 -> bf16 bits, round-to-nearest-even ----
__device__ static inline unsigned short f2bf(float f) {
  unsigned int u = __float_as_uint(f);
  u += 0x7fffu + ((u >> 16) & 1u);
  return (unsigned short)(u >> 16);
}

// ---- async global->LDS, 16B per lane ----
__device__ static inline void gload16(const unsigned short* g, unsigned short* l) {
  __builtin_amdgcn_global_load_lds(
      (const __attribute__((address_space(1))) void*)g,
      (__attribute__((address_space(3))) void*)l, 16, 0, 0);
}

// ============ kernel 1: RV2 = diag(S_tail) * (R @ Vh_tail)  (64 x IN) ========
__global__ void rv2_kernel(const float* __restrict__ Rm, const float* __restrict__ Vh_tail,
                           const float* __restrict__ S_tail, float* __restrict__ RV2) {
  const int i  = blockIdx.x * 256 + threadIdx.x;  // 0..IN_DIM-1
  const int r0 = blockIdx.y * 8;
  float acc[8] = {};
  for (int q = 0; q < RANK; ++q) {
    float v = Vh_tail[(size_t)q * IN_DIM + i];
#pragma unroll
    for (int rr = 0; rr < 8; ++rr)
      acc[rr] = fmaf(Rm[(r0 + rr) * RANK + q], v, acc[rr]);   // uniform -> s_load
  }
#pragma unroll
  for (int rr = 0; rr < 8; ++rr)
    RV2[(size_t)(r0 + rr) * IN_DIM + i] = acc[rr] * S_tail[r0 + rr];
}

// ============ kernel 2: FUSED  cvt (x->bf16)  +  W_tilde build ==============
// blocks [0, CVT_BLOCKS): grid-stride x->xb.
// blocks [CVT_BLOCKS, +WT_BLOCKS): W_tilde, VECTORIZED: each thread owns 4
// consecutive i (float4 loads of Vh_top/RV2, ushort4 stores of Wb) -> 4x fewer
// load/store instructions than the scalar R10 version (G13).
#define CVT_BLOCKS 2048
#define WT_O 16
#define WT_BLOCKS ((IN_DIM / 1024) * (OUT_DIM / WT_O))   // 4*256 = 1024
__global__ void prep_fused_kernel(const float* __restrict__ x, unsigned short* __restrict__ xb,
                                  const float* __restrict__ W,      const float* __restrict__ U_top,
                                  const float* __restrict__ S_top,  const float* __restrict__ alpha,
                                  const float* __restrict__ beta,   const float* __restrict__ U_tail,
                                  const float* __restrict__ Vh_top, const float* __restrict__ RV2,
                                  unsigned short* __restrict__ Wb) {
  const int tid = threadIdx.x;
  if (blockIdx.x < CVT_BLOCKS) {
    // ---- cvt half ----
    const long long n8 = (long long)M_DIM * IN_DIM / 8;
    long long idx = (long long)blockIdx.x * 256 + tid;
    const long long stride = (long long)CVT_BLOCKS * 256;
    for (; idx < n8; idx += stride) {
      const f32x4* p = (const f32x4*)(x + idx * 8);
      f32x4 v0 = p[0], v1 = p[1];
      s16x8 o;
      o[0] = (short)f2bf(v0[0]); o[1] = (short)f2bf(v0[1]);
      o[2] = (short)f2bf(v0[2]); o[3] = (short)f2bf(v0[3]);
      o[4] = (short)f2bf(v1[0]); o[5] = (short)f2bf(v1[1]);
      o[6] = (short)f2bf(v1[2]); o[7] = (short)f2bf(v1[3]);
      *(s16x8*)(xb + idx * 8) = o;
    }
  } else {
    // ---- wtilde half (4 i per thread) ----
    const int rem = blockIdx.x - CVT_BLOCKS;
    const int i0  = ((rem & 3) * 256 + tid) * 4;   // 0..IN_DIM-4
    const int o0  = (rem >> 2) * WT_O;             // 0..OUT_DIM-16
    float acc[WT_O][4];
#pragma unroll
    for (int o = 0; o < WT_O; ++o) {
      f32x4 w = *(const f32x4*)&W[(size_t)(o0 + o) * IN_DIM + i0];
#pragma unroll
      for (int v = 0; v < 4; ++v) acc[o][v] = w[v];
    }
#pragma unroll 2
    for (int r = 0; r < RANK; ++r) {
      float sig = fmaxf(fmaf(S_top[r], alpha[r], beta[r]), 0.f);   // uniform
      f32x4 vt = *(const f32x4*)&Vh_top[(size_t)r * IN_DIM + i0];
      f32x4 rv = *(const f32x4*)&RV2[(size_t)r * IN_DIM + i0];
#pragma unroll
      for (int v = 0; v < 4; ++v) vt[v] *= sig;
#pragma unroll
      for (int o = 0; o < WT_O; ++o) {
        const float ut = U_top[(o0 + o) * RANK + r];    // uniform -> s_load
        const float ul = U_tail[(o0 + o) * RANK + r];
#pragma unroll
        for (int v = 0; v < 4; ++v) {
          acc[o][v] = fmaf(ut, vt[v], acc[o][v]);
          acc[o][v] = fmaf(ul, rv[v], acc[o][v]);
        }
      }
    }
#pragma unroll
    for (int o = 0; o < WT_O; ++o) {
      u16x4 ov;
#pragma unroll
      for (int v = 0; v < 4; ++v) ov[v] = f2bf(acc[o][v]);
      *(u16x4*)&Wb[(size_t)(o0 + o) * IN_DIM + i0] = ov;
    }
  }
}

// ============ kernel 3: 256x256 8-phase GEMM (R12-exact, converged) =========
// 8 waves (2M x 4N), BK=64, 2-buf 128 KiB LDS, R3 staging order
// (q0:B01 q1:B23 q2:A02 q3:A13), counted waits vmcnt(4)@q1 / vmcnt(2)@q3,
// naked s_barrier + sched_barrier(0) at publication fences, XCD remap 4Mx2N.
#define BM 256
#define BN 256
#define BK 64
#define NT (IN_DIM / BK)   // 64

__global__ __launch_bounds__(512, 2) void gemm_kernel(
    const unsigned short* __restrict__ A,   // xb [M][K] bf16 bits
    const unsigned short* __restrict__ Bw,  // Wb [N][K] bf16 bits
    const float* __restrict__ bias,
    float* __restrict__ C) {
  __shared__ unsigned short lds[2][2][BM * BK];   // 128 KiB

  const int tid = threadIdx.x;
  const int l   = tid & 63;
  const int wid = tid >> 6;
  const int wr  = wid >> 2;                 // 0..1  (M split)
  const int wc  = wid & 3;                  // 0..3  (N split)

  // ---- XCD remap: xcd = bid&7 -> (mg, ng) = (xcd>>1, xcd&1); j = bid>>3 ----
  const int bid = blockIdx.x;
  const int xcd = bid & 7;
  const int j   = bid >> 3;                 // 0..127
  const int mt_ = (xcd >> 1) * 16 + (j & 15);
  const int nt_ = (xcd & 1) * 8 + (j >> 4);
  const long long tileM = (long long)mt_ * BM;
  const long long tileN = (long long)nt_ * BN;

  // ---- staging geometry (linear LDS dest, inverse-swizzled global src) ----
  const int rbase = tid >> 3;
  const int c8    = (((tid & 7) ^ (rbase & 7)) << 3);
  const unsigned short* gA = A  + (tileM + rbase) * (long long)IN_DIM + c8;
  const unsigned short* gB = Bw + (tileN + rbase) * (long long)IN_DIM + c8;

  // ---- ds_read geometry ----
  const int kgrp = l >> 4;                  // 0..3
  const int x7   = l & 7;
  const int sc0  = (((0 * 4 + kgrp) ^ x7) << 3);
  const int sc1  = (((1 * 4 + kgrp) ^ x7) << 3);
  const int rba  = (wr * 128 + (l & 15)) * BK;
  const int rbb  = (wc * 64  + (l & 15)) * BK;

  f32x4 acc[8][4] = {};

  // ---- prologue: stage tile 0 fully, drain, barrier ----
  {
    unsigned short* la = &lds[0][0][tid * 8];
    unsigned short* lb = &lds[0][1][tid * 8];
#pragma unroll
    for (int jj = 0; jj < 4; ++jj) {
      gload16(gB + (long long)jj * 64 * IN_DIM, lb + jj * 4096);
      gload16(gA + (long long)jj * 64 * IN_DIM, la + jj * 4096);
    }
    asm volatile("s_waitcnt vmcnt(0)");
    __builtin_amdgcn_s_barrier();
    __builtin_amdgcn_sched_barrier(0);      // publication fence: tile 0
  }

  int buf = 0;
  for (int t = 0; t < NT; ++t) {
    const long long ktn = (long long)(t + 1) * BK;
    const bool more = (t + 1 < NT);
    const unsigned short* lA = lds[buf][0];
    const unsigned short* lB = lds[buf][1];
    unsigned short* la1 = &lds[buf ^ 1][0][tid * 8];
    unsigned short* lb1 = &lds[buf ^ 1][1][tid * 8];

    s16x8 bfr[4][2];
#pragma unroll
    for (int q = 0; q < 4; ++q) {
      // --- ds reads for this phase ---
      if (q == 0) {
#pragma unroll
        for (int n = 0; n < 4; ++n) {
          bfr[n][0] = *(const s16x8*)&lB[rbb + n * 16 * BK + sc0];
          bfr[n][1] = *(const s16x8*)&lB[rbb + n * 16 * BK + sc1];
        }
      }
      s16x8 afr[2][2];
#pragma unroll
      for (int m2 = 0; m2 < 2; ++m2) {
        afr[m2][0] = *(const s16x8*)&lA[rba + (q * 32 + m2 * 16) * BK + sc0];
        afr[m2][1] = *(const s16x8*)&lA[rba + (q * 32 + m2 * 16) * BK + sc1];
      }

      // --- stage item q of tile t+1 into buf^1 (R3 order) ---
      if (more) {
        if (q == 0) {
          gload16(gB + ktn, lb1);
          gload16(gB + ktn + 1LL * 64 * IN_DIM, lb1 + 4096);
        } else if (q == 1) {
          gload16(gB + ktn + 2LL * 64 * IN_DIM, lb1 + 2 * 4096);
          gload16(gB + ktn + 3LL * 64 * IN_DIM, lb1 + 3 * 4096);
        } else if (q == 2) {
          gload16(gA + ktn, la1);
          gload16(gA + ktn + 2LL * 64 * IN_DIM, la1 + 2 * 4096);
        } else {
          gload16(gA + ktn + 1LL * 64 * IN_DIM, la1 + 1 * 4096);
          gload16(gA + ktn + 3LL * 64 * IN_DIM, la1 + 3 * 4096);
        }
      }

      __builtin_amdgcn_s_barrier();

      __builtin_amdgcn_s_setprio(1);
#pragma unroll
      for (int m2 = 0; m2 < 2; ++m2)
#pragma unroll
        for (int n = 0; n < 4; ++n)
#pragma unroll
          for (int kk = 0; kk < 2; ++kk)
            acc[q * 2 + m2][n] = mfma_bf16(afr[m2][kk], bfr[n][kk], acc[q * 2 + m2][n]);
      __builtin_amdgcn_s_setprio(0);

      // --- counted waits (never 0 in steady state) ---
      if (q == 1) {
        if (more) asm volatile("s_waitcnt vmcnt(4)");
        else      asm volatile("s_waitcnt vmcnt(0)");
      }
      if (q == 3 && more) {
        asm volatile("s_waitcnt vmcnt(2)");
      }
      __builtin_amdgcn_s_barrier();
      if (q == 1 || q == 3) {
        __builtin_amdgcn_sched_barrier(0);  // publication fences
      }
    }
    buf ^= 1;
  }

  // ---- epilogue: D row = m*16 + (l>>4)*4 + r ; col = n*16 + (l&15) ----
  float bv[4];
#pragma unroll
  for (int n = 0; n < 4; ++n) bv[n] = bias[tileN + wc * 64 + n * 16 + (l & 15)];
#pragma unroll
  for (int m = 0; m < 8; ++m) {
    const long long rbase_c = tileM + wr * 128 + m * 16 + (l >> 4) * 4;
#pragma unroll
    for (int r = 0; r < 4; ++r) {
      float* crow = C + (size_t)(rbase_c + r) * OUT_DIM + tileN + wc * 64 + (l & 15);
#pragma unroll
      for (int n = 0; n < 4; ++n) crow[n * 16] = acc[m][n][r] + bv[n];
    }
  }
}

extern "C" void kernel_launch(void* const* d_in, const int* in_sizes, int n_in,
                              void* d_out, int out_size, void* d_ws, size_t ws_size,
                              hipStream_t stream) {
  const float* x       = (const float*)d_in[0];
  const float* W       = (const float*)d_in[1];
  const float* bias    = (const float*)d_in[2];
  const float* U_top   = (const float*)d_in[3];
  const float* S_top   = (const float*)d_in[4];
  const float* Vh_top  = (const float*)d_in[5];
  const float* U_tail  = (const float*)d_in[6];
  const float* S_tail  = (const float*)d_in[7];
  const float* Vh_tail = (const float*)d_in[8];
  const float* alpha   = (const float*)d_in[9];
  const float* beta    = (const float*)d_in[10];
  const float* Rm      = (const float*)d_in[11];

  char* ws = (char*)d_ws;
  unsigned short* xb  = (unsigned short*)ws;                                  // 128 MB
  unsigned short* Wb  = (unsigned short*)(ws + (size_t)134217728);            // 32 MB
  float*          RV2 = (float*)(ws + (size_t)134217728 + 33554432);          // 1 MB

  rv2_kernel<<<dim3(IN_DIM / 256, RANK / 8), 256, 0, stream>>>(Rm, Vh_tail, S_tail, RV2);
  prep_fused_kernel<<<CVT_BLOCKS + WT_BLOCKS, 256, 0, stream>>>(
      x, xb, W, U_top, S_top, alpha, beta, U_tail, Vh_top, RV2, Wb);
  gemm_kernel<<<(M_DIM / BM) * (OUT_DIM / BN), 512, 0, stream>>>(xb, Wb, bias,
                                                                 (float*)d_out);
}